// Round 1
// baseline (760.269 us; speedup 1.0000x reference)
//
#include <hip/hip_runtime.h>

// Problem constants (from setup_inputs): x:(8,32,32,64,64) f32 -> out:(8,32,48,96,96) f32
// variance=1: out = 2*log( trilinear( exp(x/2) ) ), identity grid, align_corners=True.
constexpr int N   = 8;
constexpr int C   = 32;
constexpr int Din = 32, Hin = 64, Win = 64;
constexpr int Do  = 48, Ho  = 96, Wo  = 96;

constexpr int   WQ       = Wo / 4;                          // 24 float4-chunks per row
constexpr int   NTHREADS = N * C * Do * Ho * WQ;            // 28,311,552
constexpr int   BLOCK    = 256;
constexpr int   NBLOCKS  = NTHREADS / BLOCK;                // 110,592 (exact)

__global__ __launch_bounds__(BLOCK)
void resample3d_var_kernel(const float* __restrict__ in, float* __restrict__ out) {
    int tid = blockIdx.x * BLOCK + threadIdx.x;

    // decompose: tid = (((nc*Do + zo)*Ho + yo)*WQ) + xq
    int xq = tid % WQ;
    int t  = tid / WQ;
    int yo = t % Ho;  t /= Ho;
    int zo = t % Do;  t /= Do;          // t = n*C + c  (0..255)

    const float* __restrict__ xb = in + (size_t)t * (Din * Hin * Win);

    // y/z source coords + weights (align_corners identity grid)
    float fy = yo * (float)(Hin - 1) / (float)(Ho - 1);   // yo * 63/95
    float fz = zo * (float)(Din - 1) / (float)(Do - 1);   // zo * 31/47
    int y0 = (int)fy;  float wy1 = fy - (float)y0;
    int z0 = (int)fz;  float wz1 = fz - (float)z0;
    int y1 = y0 + 1; if (y1 > Hin - 1) { y1 = Hin - 1; wy1 = 0.0f; }
    int z1 = z0 + 1; if (z1 > Din - 1) { z1 = Din - 1; wz1 = 0.0f; }
    float wy0 = 1.0f - wy1, wz0 = 1.0f - wz1;

    // bilinear (z,y) corner weights
    float w00 = wz0 * wy0;   // z0,y0
    float w01 = wz0 * wy1;   // z0,y1
    float w10 = wz1 * wy0;   // z1,y0
    float w11 = wz1 * wy1;   // z1,y1

    const float* __restrict__ r00 = xb + z0 * (Hin * Win) + y0 * Win;
    const float* __restrict__ r01 = xb + z0 * (Hin * Win) + y1 * Win;
    const float* __restrict__ r10 = xb + z1 * (Hin * Win) + y0 * Win;
    const float* __restrict__ r11 = xb + z1 * (Hin * Win) + y1 * Win;

    int xo0 = xq * 4;
    float4 res;
    float* rp = &res.x;

#pragma unroll
    for (int k = 0; k < 4; ++k) {
        int   xo  = xo0 + k;
        float fx  = xo * (float)(Win - 1) / (float)(Wo - 1);  // xo * 63/95
        int   x0  = (int)fx;
        float wx1 = fx - (float)x0;
        int   x1  = x0 + 1; if (x1 > Win - 1) { x1 = Win - 1; wx1 = 0.0f; }
        float wx0 = 1.0f - wx1;

        float e000 = __expf(r00[x0] * 0.5f);
        float e001 = __expf(r00[x1] * 0.5f);
        float e010 = __expf(r01[x0] * 0.5f);
        float e011 = __expf(r01[x1] * 0.5f);
        float e100 = __expf(r10[x0] * 0.5f);
        float e101 = __expf(r10[x1] * 0.5f);
        float e110 = __expf(r11[x0] * 0.5f);
        float e111 = __expf(r11[x1] * 0.5f);

        float acc = w00 * (wx0 * e000 + wx1 * e001)
                  + w01 * (wx0 * e010 + wx1 * e011)
                  + w10 * (wx0 * e100 + wx1 * e101)
                  + w11 * (wx0 * e110 + wx1 * e111);

        rp[k] = 2.0f * __logf(acc);
    }

    size_t oidx = ((((size_t)t * Do + zo) * Ho + yo) * Wo) + xo0;
    *reinterpret_cast<float4*>(out + oidx) = res;
}

extern "C" void kernel_launch(void* const* d_in, const int* in_sizes, int n_in,
                              void* d_out, int out_size, void* d_ws, size_t ws_size,
                              hipStream_t stream) {
    const float* x = (const float*)d_in[0];
    float* out = (float*)d_out;
    resample3d_var_kernel<<<NBLOCKS, BLOCK, 0, stream>>>(x, out);
}

// Round 2
// 277.216 us; speedup vs baseline: 2.7425x; 2.7425x over previous
//
#include <hip/hip_runtime.h>

// x:(8,32,32,64,64) f32 -> out:(8,32,48,96,96) f32
// variance=1: out = 2*log( trilinear( exp(x/2) ) ), identity grid, align_corners=True.
// Separable scheme: one wave per output row (nc,zo,yo).
//   Stage F[x] = sum_{zy corners} w * exp(in[z,y,x]/2)  (x = lane, coalesced loads)
//   Then out[xo] = 2*log( wx0*F[x0] + wx1*F[x1] )       (96 outputs per wave)
constexpr int N   = 8;
constexpr int C   = 32;
constexpr int Din = 32, Hin = 64, Win = 64;
constexpr int Do  = 48, Ho  = 96, Wo  = 96;

constexpr int ROWS    = N * C * Do * Ho;      // 1,179,648 output rows
constexpr int WAVES   = 4;                    // waves per block
constexpr int BLOCK   = WAVES * 64;           // 256
constexpr int NBLOCKS = ROWS / WAVES;         // 294,912 (exact)

__global__ __launch_bounds__(BLOCK)
void resample3d_var_kernel(const float* __restrict__ in, float* __restrict__ out) {
    __shared__ float Fs[WAVES][Win];

    const int wave = threadIdx.x >> 6;
    const int lane = threadIdx.x & 63;
    const int row  = blockIdx.x * WAVES + wave;

    // row = ((nc*Do + zo)*Ho + yo)
    const int yo = row % Ho;
    int t        = row / Ho;
    const int zo = t % Do;
    const int nc = t / Do;

    // y/z source coords + bilinear weights (align_corners identity grid)
    float fy = yo * ((float)(Hin - 1) / (float)(Ho - 1));   // yo * 63/95
    float fz = zo * ((float)(Din - 1) / (float)(Do - 1));   // zo * 31/47
    int y0 = (int)fy;  float wy1 = fy - (float)y0;
    int z0 = (int)fz;  float wz1 = fz - (float)z0;
    int y1 = y0 + 1; if (y1 > Hin - 1) { y1 = Hin - 1; wy1 = 0.0f; }
    int z1 = z0 + 1; if (z1 > Din - 1) { z1 = Din - 1; wz1 = 0.0f; }
    float wy0 = 1.0f - wy1, wz0 = 1.0f - wz1;

    float w00 = wz0 * wy0, w01 = wz0 * wy1, w10 = wz1 * wy0, w11 = wz1 * wy1;

    const float* __restrict__ xb  = in + (size_t)nc * (Din * Hin * Win);
    const float* __restrict__ r00 = xb + (z0 * Hin + y0) * Win;
    const float* __restrict__ r01 = xb + (z0 * Hin + y1) * Win;
    const float* __restrict__ r10 = xb + (z1 * Hin + y0) * Win;
    const float* __restrict__ r11 = xb + (z1 * Hin + y1) * Win;

    // Fused (z,y)-bilinear of exp(x/2), one x-column per lane. Coalesced loads.
    float F = w00 * __expf(r00[lane] * 0.5f)
            + w01 * __expf(r01[lane] * 0.5f)
            + w10 * __expf(r10[lane] * 0.5f)
            + w11 * __expf(r11[lane] * 0.5f);
    Fs[wave][lane] = F;
    __syncthreads();

    const size_t obase = (((size_t)nc * Do + zo) * Ho + yo) * Wo;

    // x-linear + log for 96 outputs: xo = lane, then xo = 64 + lane (lane < 32)
    {
        int   xo  = lane;
        float fx  = xo * ((float)(Win - 1) / (float)(Wo - 1)); // xo * 63/95
        int   x0  = (int)fx;
        float wx1 = fx - (float)x0;
        int   x1  = x0 + 1; if (x1 > Win - 1) x1 = Win - 1;    // wx1==0 there
        float v   = (1.0f - wx1) * Fs[wave][x0] + wx1 * Fs[wave][x1];
        out[obase + xo] = 2.0f * __logf(v);
    }
    if (lane < 32) {
        int   xo  = 64 + lane;
        float fx  = xo * ((float)(Win - 1) / (float)(Wo - 1));
        int   x0  = (int)fx;
        float wx1 = fx - (float)x0;
        int   x1  = x0 + 1; if (x1 > Win - 1) x1 = Win - 1;
        float v   = (1.0f - wx1) * Fs[wave][x0] + wx1 * Fs[wave][x1];
        out[obase + xo] = 2.0f * __logf(v);
    }
}

extern "C" void kernel_launch(void* const* d_in, const int* in_sizes, int n_in,
                              void* d_out, int out_size, void* d_ws, size_t ws_size,
                              hipStream_t stream) {
    const float* x = (const float*)d_in[0];
    float* out = (float*)d_out;
    resample3d_var_kernel<<<NBLOCKS, BLOCK, 0, stream>>>(x, out);
}

// Round 3
// 130.286 us; speedup vs baseline: 5.8354x; 2.1277x over previous
//
#include <hip/hip_runtime.h>

// x:(8,32,32,64,64) f32 -> out:(8,32,48,96,96) f32
// variance=1: out = 2*log( trilinear( exp(x/2) ) ), identity grid, align_corners=True.
//
// Block = one (nc, zo). Stage z-combined exp plane G[64][64] in LDS once:
//   G[y][x] = wz0*exp(in[z0,y,x]/2) + wz1*exp(in[z1,y,x]/2)
// Then each wave produces 24 output rows: F[x] = y-lerp of G (registers, x=lane),
// x-lerp via ds_bpermute with per-wave hoisted weights, then 2*log().
constexpr int N = 8, C = 32, Din = 32, Hin = 64, Win = 64;
constexpr int Do = 48, Ho = 96, Wo = 96;

constexpr int BLOCK        = 256;
constexpr int NBLOCKS      = N * C * Do;   // 12288, one per (nc, zo)
constexpr int WAVES        = BLOCK / 64;   // 4
constexpr int ROWS_PER_WAVE = Ho / WAVES;  // 24

__global__ __launch_bounds__(BLOCK)
void resample3d_var_kernel(const float* __restrict__ in, float* __restrict__ out) {
    __shared__ float G[Hin][Win];   // 16 KB

    const int bid = blockIdx.x;
    const int zo  = bid % Do;
    const int nc  = bid / Do;

    // z weights (block-uniform). Exact division: edge zo=47 -> fz==31.0 exactly.
    float fz = (float)(zo * (Din - 1)) / (float)(Do - 1);
    int   z0 = (int)fz;
    float wz1 = fz - (float)z0;
    int   z1 = min(z0 + 1, Din - 1);
    float wz0 = 1.0f - wz1;

    const float* __restrict__ p0 = in + ((size_t)nc * Din + z0) * (Hin * Win);
    const float* __restrict__ p1 = in + ((size_t)nc * Din + z1) * (Hin * Win);

    // ---- stage G: 4096 floats, 256 threads, float4 per iter ----
    const int tid = threadIdx.x;
    const int sy  = tid >> 4;            // 0..15
    const int sx  = (tid & 15) << 2;     // 0,4,...,60
#pragma unroll
    for (int k = 0; k < 4; ++k) {
        int y = sy + k * 16;
        const float4 a = *reinterpret_cast<const float4*>(p0 + y * Win + sx);
        const float4 b = *reinterpret_cast<const float4*>(p1 + y * Win + sx);
        float4 g;
        g.x = wz0 * __expf(a.x * 0.5f) + wz1 * __expf(b.x * 0.5f);
        g.y = wz0 * __expf(a.y * 0.5f) + wz1 * __expf(b.y * 0.5f);
        g.z = wz0 * __expf(a.z * 0.5f) + wz1 * __expf(b.z * 0.5f);
        g.w = wz0 * __expf(a.w * 0.5f) + wz1 * __expf(b.w * 0.5f);
        *reinterpret_cast<float4*>(&G[y][sx]) = g;
    }
    __syncthreads();

    const int wave = tid >> 6;
    const int lane = tid & 63;

    // ---- hoisted x-interp params (per lane, reused for all 24 rows) ----
    // chunk A: xo = lane (0..63); chunk B: xo = 64 + (lane&31) (stores masked to lane<32)
    int xoA = lane;
    int xoB = 64 + (lane & 31);
    float fxA = (float)(xoA * (Win - 1)) / (float)(Wo - 1);   // exact at edges
    float fxB = (float)(xoB * (Win - 1)) / (float)(Wo - 1);
    int   x0A = (int)fxA;  float wxA = fxA - (float)x0A;
    int   x0B = (int)fxB;  float wxB = fxB - (float)x0B;
    int   aA0 = x0A << 2;
    int   aA1 = min(x0A + 1, Win - 1) << 2;
    int   aB0 = x0B << 2;
    int   aB1 = min(x0B + 1, Win - 1) << 2;

    const int yo0 = wave * ROWS_PER_WAVE;
    float* op = out + (((size_t)nc * Do + zo) * Ho + yo0) * Wo;

    constexpr float TWO_LN2 = 1.3862943611198906f;  // 2*ln2 : 2*logf(v) == TWO_LN2*log2(v)

    for (int r = 0; r < ROWS_PER_WAVE; ++r) {
        int   yo = yo0 + r;
        float fy = (float)(yo * (Hin - 1)) / (float)(Ho - 1);  // exact at yo=95
        int   y0 = (int)fy;
        float wy1 = fy - (float)y0;
        int   y1 = min(y0 + 1, Hin - 1);

        float g0 = G[y0][lane];
        float g1 = G[y1][lane];
        float F  = g0 + wy1 * (g1 - g0);   // F[x]=lane x of y/z-combined row

        int Fi = __builtin_bit_cast(int, F);
        float FA0 = __builtin_bit_cast(float, __builtin_amdgcn_ds_bpermute(aA0, Fi));
        float FA1 = __builtin_bit_cast(float, __builtin_amdgcn_ds_bpermute(aA1, Fi));
        float vA  = FA0 + wxA * (FA1 - FA0);
        op[lane] = TWO_LN2 * __log2f(vA);

        float FB0 = __builtin_bit_cast(float, __builtin_amdgcn_ds_bpermute(aB0, Fi));
        float FB1 = __builtin_bit_cast(float, __builtin_amdgcn_ds_bpermute(aB1, Fi));
        float vB  = FB0 + wxB * (FB1 - FB0);
        if (lane < 32) op[64 + lane] = TWO_LN2 * __log2f(vB);

        op += Wo;
    }
}

extern "C" void kernel_launch(void* const* d_in, const int* in_sizes, int n_in,
                              void* d_out, int out_size, void* d_ws, size_t ws_size,
                              hipStream_t stream) {
    const float* x = (const float*)d_in[0];
    float* out = (float*)d_out;
    resample3d_var_kernel<<<NBLOCKS, BLOCK, 0, stream>>>(x, out);
}

// Round 4
// 124.921 us; speedup vs baseline: 6.0860x; 1.0430x over previous
//
#include <hip/hip_runtime.h>

// x:(8,32,32,64,64) f32 -> out:(8,32,48,96,96) f32
// variance=1: out = 2*log( trilinear( exp(x/2) ) ), identity grid, align_corners=True.
//
// Block = one (nc, zo).
//  Phase 1: G[y][x]   = wz0*exp(in[z0,y,x]/2) + wz1*exp(in[z1,y,x]/2)   (LDS, 16 KB)
//  Phase 2: F2[yr][x] = y-lerp of G for 48 output rows (half of Ho)     (LDS, 13 KB, pad 68)
//  Phase 3: each thread emits one float4 of consecutive outputs:
//           8 ds_read_b32 + 4 lerps + 4 logs + 1 global_store_dwordx4 (chunk = c*16B, contiguous)
constexpr int N = 8, C = 32, Din = 32, Hin = 64, Win = 64;
constexpr int Do = 48, Ho = 96, Wo = 96;

constexpr int BLOCK   = 256;
constexpr int NBLOCKS = N * C * Do;        // 12288 blocks, one per (nc, zo)
constexpr int HROWS   = Ho / 2;            // 48 output rows per half
constexpr int F2PAD   = 68;                // 64 + 4: break cross-row bank aliasing
constexpr int QUADS   = HROWS * (Wo / 4);  // 1152 float4 chunks per half

__global__ __launch_bounds__(BLOCK)
void resample3d_var_kernel(const float* __restrict__ in, float* __restrict__ out) {
    __shared__ float G[Hin][Win];          // 16384 B
    __shared__ float F2[HROWS][F2PAD];     // 13056 B

    const int tid = threadIdx.x;
    const int bid = blockIdx.x;
    const int zo  = bid % Do;
    const int nc  = bid / Do;

    // z weights (block-uniform)
    float fz  = (float)(zo * (Din - 1)) * (1.0f / (float)(Do - 1));
    int   z0  = (int)fz;
    float wz1 = fz - (float)z0;
    int   z1  = min(z0 + 1, Din - 1);
    float wz0 = 1.0f - wz1;

    const float* __restrict__ p0 = in + ((size_t)nc * Din + z0) * (Hin * Win);
    const float* __restrict__ p1 = in + ((size_t)nc * Din + z1) * (Hin * Win);

    // ---- Phase 1: stage G (4096 floats; float4 loads, 8 exps per iter) ----
    {
        const int sy = tid >> 4;             // 0..15
        const int sx = (tid & 15) << 2;      // 0,4,...,60
#pragma unroll
        for (int k = 0; k < 4; ++k) {
            int y = sy + k * 16;
            const float4 a = *reinterpret_cast<const float4*>(p0 + y * Win + sx);
            const float4 b = *reinterpret_cast<const float4*>(p1 + y * Win + sx);
            float4 g;
            g.x = wz0 * __expf(a.x * 0.5f) + wz1 * __expf(b.x * 0.5f);
            g.y = wz0 * __expf(a.y * 0.5f) + wz1 * __expf(b.y * 0.5f);
            g.z = wz0 * __expf(a.z * 0.5f) + wz1 * __expf(b.z * 0.5f);
            g.w = wz0 * __expf(a.w * 0.5f) + wz1 * __expf(b.w * 0.5f);
            *reinterpret_cast<float4*>(&G[y][sx]) = g;
        }
    }
    __syncthreads();

    const size_t obase = ((size_t)nc * Do + zo) * (size_t)(Ho * Wo);
    constexpr float TWO_LN2 = 1.3862943611198906f;   // 2*logf(v) == TWO_LN2*log2f(v)

    for (int h = 0; h < 2; ++h) {
        // ---- Phase 2: stage F2 for this half (48 rows x 64 x) ----
        {
            const int x   = tid & 63;
            const int yr0 = tid >> 6;        // wave id: per-wave uniform row
#pragma unroll
            for (int j = 0; j < 12; ++j) {
                int yrow = j * 4 + yr0;
                int yo   = h * HROWS + yrow;
                float fy  = (float)(yo * (Hin - 1)) * (1.0f / (float)(Ho - 1));
                int   y0  = (int)fy;
                float wy1 = fy - (float)y0;
                int   y1  = min(y0 + 1, Hin - 1);
                float g0 = G[y0][x], g1 = G[y1][x];
                F2[yrow][x] = g0 + wy1 * (g1 - g0);
            }
        }
        __syncthreads();

        // ---- Phase 3: 1152 float4 chunks; chunk c at byte offset c*16 (contiguous) ----
        float* __restrict__ ob = out + obase + (size_t)h * (HROWS * Wo);
#pragma unroll
        for (int k = 0; k < 5; ++k) {
            int c = k * BLOCK + tid;
            if (c < QUADS) {
                int row = (c * 2731) >> 16;          // c / 24, exact for c < 1536
                int q   = c - row * 24;
                float4 o;
                float* op = &o.x;
#pragma unroll
                for (int i = 0; i < 4; ++i) {
                    int   xo  = q * 4 + i;
                    float fx  = (float)(xo * (Win - 1)) * (1.0f / (float)(Wo - 1));
                    int   x0  = (int)fx;
                    float wx1 = fx - (float)x0;
                    int   x1  = min(x0 + 1, Win - 1);
                    float F0 = F2[row][x0], F1 = F2[row][x1];
                    float v  = F0 + wx1 * (F1 - F0);
                    op[i] = TWO_LN2 * __log2f(v);
                }
                *reinterpret_cast<float4*>(ob + (size_t)c * 4) = o;
            }
        }
        if (h == 0) __syncthreads();   // WAR: F2 overwrite for half 1
    }
}

extern "C" void kernel_launch(void* const* d_in, const int* in_sizes, int n_in,
                              void* d_out, int out_size, void* d_ws, size_t ws_size,
                              hipStream_t stream) {
    const float* x = (const float*)d_in[0];
    float* out = (float*)d_out;
    resample3d_var_kernel<<<NBLOCKS, BLOCK, 0, stream>>>(x, out);
}